// Round 7
// baseline (585.974 us; speedup 1.0000x reference)
//
#include <hip/hip_runtime.h>

#define NUM_RELS 19
#define NPB 256        // nodes per bucket (power of 2)
#define NPB_SHIFT 8
#define MAXB 400       // max buckets (N <= 102400)
#define PCAP 16        // partition stage capacity per bucket (flush in units of 8)

typedef _Float16 half8 __attribute__((ext_vector_type(8)));
typedef float floatx4 __attribute__((ext_vector_type(4)));

// ---------------- bucket histogram: bcnt[b] = #edges with dst in bucket b ----------------

__global__ __launch_bounds__(256) void bhist_kernel(const int* __restrict__ dst,
                                                    int* __restrict__ bcnt, int E, int B) {
    __shared__ int h[MAXB];
    for (int i = threadIdx.x; i < B; i += 256) h[i] = 0;
    __syncthreads();
    for (int e = blockIdx.x * blockDim.x + threadIdx.x; e < E; e += gridDim.x * blockDim.x)
        atomicAdd(&h[dst[e] >> NPB_SHIFT], 1);
    __syncthreads();
    for (int i = threadIdx.x; i < B; i += 256)
        if (h[i]) atomicAdd(&bcnt[i], h[i]);
}

// ---------------- bucket scan: pbase = exclusive scan of 8-aligned counts; gcur = pbase ----------------

__global__ __launch_bounds__(512) void bscan_kernel(const int* __restrict__ bcnt,
                                                    int* __restrict__ pbase,
                                                    int* __restrict__ gcur, int B) {
    __shared__ int lds[512];
    int t = threadIdx.x;
    int c = (t < B) ? ((bcnt[t] + 7) & ~7) : 0;
    lds[t] = c;
    __syncthreads();
    for (int off = 1; off < 512; off <<= 1) {
        int x = (t >= off) ? lds[t - off] : 0;
        __syncthreads();
        lds[t] += x;
        __syncthreads();
    }
    if (t < B) {
        int p = lds[t] - c;
        pbase[t] = p;
        gcur[t] = p;
    }
}

// ---------------- partition: bin edges into bucket regions with line-granular flushes ----------------
// Block-synchronous rounds: stage records in LDS per bucket, flush multiples of 8 records
// (64B, 8-aligned since pbase is 8-aligned) from one lane -> same-XCD L2 merges to full lines.
// Stage overflow (pos >= PCAP, rare with uniform dst) spills directly to global — correctness valve.

__global__ __launch_bounds__(512) void partition_kernel(
    const int* __restrict__ src, const int* __restrict__ dst, const int* __restrict__ etype,
    int* __restrict__ gcur, uint2* __restrict__ recs, int E, int B, int chunk) {
    __shared__ uint2 stage[MAXB * PCAP];  // 400*16*8B = 51.2KB
    __shared__ int scnt[MAXB];
    for (int i = threadIdx.x; i < B; i += 512) scnt[i] = 0;
    __syncthreads();

    int e0 = blockIdx.x * chunk;
    int e1 = min(E, e0 + chunk);
    for (int base = e0; base < e1; base += 512) {
        int e = base + (int)threadIdx.x;
        if (e < e1) {
            int d = dst[e];
            uint2 rec;
            rec.x = ((unsigned)src[e] << 5) | (unsigned)etype[e];
            rec.y = (unsigned)d;
            int b = d >> NPB_SHIFT;
            int pos = atomicAdd(&scnt[b], 1);
            if (pos < PCAP) {
                stage[b * PCAP + pos] = rec;
            } else {  // spill valve
                int g = atomicAdd(&gcur[b], 1);
                recs[g] = rec;
            }
        }
        __syncthreads();
        for (int bb = threadIdx.x; bb < B; bb += 512) {
            int c = scnt[bb];
            if (c > PCAP) c = PCAP;
            int nf = c & ~7;
            if (nf) {
                int g = atomicAdd(&gcur[bb], nf);
                for (int i = 0; i < nf; ++i) recs[g + i] = stage[bb * PCAP + i];
                for (int i = 0; i < c - nf; ++i) stage[bb * PCAP + i] = stage[bb * PCAP + nf + i];
            }
            scnt[bb] = c - nf;
        }
        __syncthreads();
    }
    // drain remainders (<8 per bucket per block; contiguous per claim)
    for (int bb = threadIdx.x; bb < B; bb += 512) {
        int c = scnt[bb];
        if (c > PCAP) c = PCAP;
        if (c) {
            int g = atomicAdd(&gcur[bb], c);
            for (int i = 0; i < c; ++i) recs[g + i] = stage[bb * PCAP + i];
        }
    }
}

// ---------------- Layer 1 per bucket: LDS (node,rel) counts -> h1 = relu(b1 + sum_r cnt*W1[r]) ----------------

__global__ __launch_bounds__(256) void blayer1_kernel(
    const uint2* __restrict__ recs, const int* __restrict__ pbase, const int* __restrict__ bcnt,
    const float* __restrict__ W1, const float* __restrict__ b1, float* __restrict__ h1, int N) {
    __shared__ int cnt[NPB * NUM_RELS];  // 19.4KB
    __shared__ float W1s[NUM_RELS * 32];
    __shared__ float b1s[32];
    for (int i = threadIdx.x; i < NPB * NUM_RELS; i += 256) cnt[i] = 0;
    for (int i = threadIdx.x; i < NUM_RELS * 32; i += 256) W1s[i] = W1[i];
    if (threadIdx.x < 32) b1s[threadIdx.x] = b1[threadIdx.x];
    __syncthreads();

    int b = blockIdx.x;
    int p0 = pbase[b], n = bcnt[b];
    for (int i = threadIdx.x; i < n; i += 256) {
        uint2 rec = recs[p0 + i];
        atomicAdd(&cnt[(rec.y & (NPB - 1)) * NUM_RELS + (rec.x & 31)], 1);
    }
    __syncthreads();

    int o = threadIdx.x & 31, hw = threadIdx.x >> 5;  // 8 half-waves
    int v0 = b << NPB_SHIFT;
    for (int k = hw; k < NPB; k += 8) {
        int v = v0 + k;
        if (v >= N) break;
        float acc = b1s[o];
        const int* cp = &cnt[k * NUM_RELS];
#pragma unroll
        for (int r = 0; r < NUM_RELS; ++r) acc += (float)cp[r] * W1s[r * 32 + o];
        h1[(size_t)v * 32 + o] = fmaxf(acc, 0.f);
    }
}

// ---------------- W2 -> f16 B-fragment swizzle (unchanged, round-6 verified) ----------------

__global__ void w2swz_kernel(const float* __restrict__ W2, _Float16* __restrict__ W2F) {
    int idx = blockIdx.x * blockDim.x + threadIdx.x;
    if (idx >= NUM_RELS * 2 * 64 * 8) return;
    int j = idx & 7, lane = (idx >> 3) & 63, nt = (idx >> 9) & 1, r = idx >> 10;
    int k = (lane >> 4) * 8 + j, n = nt * 16 + (lane & 15);
    W2F[idx] = (_Float16)W2[r * 1024 + k * 32 + n];
}

// ---------------- Transform via MFMA: g[r] = h1 @ W2[r]  (f16 output; round-6 verified) ----------------

__global__ __launch_bounds__(256) void transform_kernel(
    const float* __restrict__ h1, const _Float16* __restrict__ W2F,
    _Float16* __restrict__ g, int N) {
    int lane = threadIdx.x & 63;
    int tile = blockIdx.x * 4 + (threadIdx.x >> 6);
    int v0 = tile * 16;
    if (v0 >= N) return;

    const float* hrow = h1 + (size_t)(v0 + (lane & 15)) * 32 + (lane >> 4) * 8;
    float4 p0 = *(const float4*)hrow;
    float4 p1 = *(const float4*)(hrow + 4);
    half8 a;
    a[0] = (_Float16)p0.x; a[1] = (_Float16)p0.y; a[2] = (_Float16)p0.z; a[3] = (_Float16)p0.w;
    a[4] = (_Float16)p1.x; a[5] = (_Float16)p1.y; a[6] = (_Float16)p1.z; a[7] = (_Float16)p1.w;

    floatx4 zero = {0.f, 0.f, 0.f, 0.f};
    int row = (lane >> 4) * 4;
    int col = lane & 15;
    for (int r = 0; r < NUM_RELS; ++r) {
        _Float16* gbase = g + ((size_t)r * N + v0) * 32;
#pragma unroll
        for (int nt = 0; nt < 2; ++nt) {
            half8 bfrag = *(const half8*)(W2F + ((r * 2 + nt) * 64 + lane) * 8);
            floatx4 d = __builtin_amdgcn_mfma_f32_16x16x32_f16(a, bfrag, zero, 0, 0, 0);
#pragma unroll
            for (int reg = 0; reg < 4; ++reg) {
                gbase[(row + reg) * 32 + nt * 16 + col] = (_Float16)d[reg];
            }
        }
    }
}

// ---------------- Aggregate per bucket + fused layer 3 ----------------
// LDS z2 tile (256 nodes x 32 ch, init b2). Per record: broadcast 8B read + random 64B g-row
// load (L3-resident) + ds_add_f32 (bank-conflict-free: lane o -> bank o). 4-deep unroll for
// memory-latency overlap. Epilogue: out = relu(z2) @ W3 + b3, written straight to d_out.

__global__ __launch_bounds__(1024) void agg_kernel(
    const _Float16* __restrict__ g, const uint2* __restrict__ recs,
    const int* __restrict__ pbase, const int* __restrict__ bcnt,
    const float* __restrict__ b2, const float* __restrict__ W3, const float* __restrict__ b3,
    float* __restrict__ out, int N) {
    __shared__ float z2[NPB * 32];  // 32KB
    __shared__ float W3s[1024];
    __shared__ float b3s[32];
    if (threadIdx.x < 1024) W3s[threadIdx.x] = W3[threadIdx.x];
    if (threadIdx.x < 32) b3s[threadIdx.x] = b3[threadIdx.x];
    for (int i = threadIdx.x; i < NPB * 32; i += 1024) z2[i] = b2[i & 31];
    __syncthreads();

    int b = blockIdx.x;
    int p0 = pbase[b], n = bcnt[b];
    int o = threadIdx.x & 31, hw = threadIdx.x >> 5;  // 32 half-waves
    const int sN32 = N * 32;

    const uint2* rp = recs + p0;
    for (int i = hw; i < n; i += 128) {  // 4 records per half-wave iteration (ILP)
        int i1 = i + 32, i2 = i + 64, i3 = i + 96;
        float v0f = 0.f, v1f = 0.f, v2f = 0.f, v3f = 0.f;
        int l0 = -1, l1 = -1, l2 = -1, l3 = -1;
        {
            uint2 rec = rp[i];
            l0 = rec.y & (NPB - 1);
            v0f = (float)g[(size_t)(rec.x & 31) * sN32 + (rec.x >> 5) * 32 + o];
        }
        if (i1 < n) {
            uint2 rec = rp[i1];
            l1 = rec.y & (NPB - 1);
            v1f = (float)g[(size_t)(rec.x & 31) * sN32 + (rec.x >> 5) * 32 + o];
        }
        if (i2 < n) {
            uint2 rec = rp[i2];
            l2 = rec.y & (NPB - 1);
            v2f = (float)g[(size_t)(rec.x & 31) * sN32 + (rec.x >> 5) * 32 + o];
        }
        if (i3 < n) {
            uint2 rec = rp[i3];
            l3 = rec.y & (NPB - 1);
            v3f = (float)g[(size_t)(rec.x & 31) * sN32 + (rec.x >> 5) * 32 + o];
        }
        atomicAdd(&z2[l0 * 32 + o], v0f);
        if (l1 >= 0) atomicAdd(&z2[l1 * 32 + o], v1f);
        if (l2 >= 0) atomicAdd(&z2[l2 * 32 + o], v2f);
        if (l3 >= 0) atomicAdd(&z2[l3 * 32 + o], v3f);
    }
    __syncthreads();

    int v0 = b << NPB_SHIFT;
    for (int k = hw; k < NPB; k += 32) {
        int v = v0 + k;
        if (v >= N) break;
        float h2v = fmaxf(z2[k * 32 + o], 0.f);
        float acc3 = b3s[o];
#pragma unroll
        for (int i = 0; i < 32; ++i) acc3 = fmaf(__shfl(h2v, i, 32), W3s[i * 32 + o], acc3);
        out[(size_t)v * 32 + o] = acc3;
    }
}

// ---------------- Host launcher ----------------

extern "C" void kernel_launch(void* const* d_in, const int* in_sizes, int n_in,
                              void* d_out, int out_size, void* d_ws, size_t ws_size,
                              hipStream_t stream) {
    const int* src   = (const int*)d_in[0];
    const int* dst   = (const int*)d_in[1];
    const int* etype = (const int*)d_in[2];
    const float* W1  = (const float*)d_in[4];
    const float* b1  = (const float*)d_in[5];
    const float* W2  = (const float*)d_in[6];
    const float* b2  = (const float*)d_in[7];
    const float* W3  = (const float*)d_in[8];
    const float* b3  = (const float*)d_in[9];
    float* out = (float*)d_out;

    int E = in_sizes[0];
    int N = out_size / 32;
    int B = (N + NPB - 1) >> NPB_SHIFT;  // 391 for N=100000

    char* ws = (char*)d_ws;
    size_t off = 0;
    auto alloc = [&](size_t bytes) {
        void* p = ws + off;
        off = (off + bytes + 255) & ~(size_t)255;
        return p;
    };
    float* h1     = (float*)alloc((size_t)N * 32 * 4);
    int* bcnt     = (int*)alloc((size_t)MAXB * 4);
    int* pbase    = (int*)alloc((size_t)MAXB * 4);
    int* gcur     = (int*)alloc((size_t)MAXB * 4);
    uint2* recs   = (uint2*)alloc(((size_t)E + 8 * MAXB + 64) * 8);
    _Float16* g   = (_Float16*)alloc((size_t)NUM_RELS * N * 32 * 2);
    _Float16* W2F = (_Float16*)alloc((size_t)NUM_RELS * 2 * 64 * 8 * 2);

    hipMemsetAsync(bcnt, 0, (size_t)B * 4, stream);
    bhist_kernel<<<256, 256, 0, stream>>>(dst, bcnt, E, B);
    bscan_kernel<<<1, 512, 0, stream>>>(bcnt, pbase, gcur, B);

    int chunk = (E + 127) / 128;
    partition_kernel<<<128, 512, 0, stream>>>(src, dst, etype, gcur, recs, E, B, chunk);

    blayer1_kernel<<<B, 256, 0, stream>>>(recs, pbase, bcnt, W1, b1, h1, N);

    w2swz_kernel<<<(NUM_RELS * 2 * 64 * 8 + 255) / 256, 256, 0, stream>>>(W2, W2F);
    int ntiles = (N + 15) / 16;
    transform_kernel<<<(ntiles + 3) / 4, 256, 0, stream>>>(h1, W2F, g, N);

    agg_kernel<<<B, 1024, 0, stream>>>(g, recs, pbase, bcnt, b2, W3, b3, out, N);
}